// Round 15
// baseline (225.179 us; speedup 1.0000x reference)
//
#include <hip/hip_runtime.h>
#include <math.h>

// Causal self-attention, B=4, T=2048, E=1024, H=16, D=64. fp32 in/out,
// bf16 MFMA internally.

typedef __bf16 bf16x8 __attribute__((ext_vector_type(8)));
typedef float f32x4 __attribute__((ext_vector_type(4)));
typedef unsigned int u32x4 __attribute__((ext_vector_type(4)));
typedef unsigned int uint;
typedef unsigned short ushort;

#define B_ 4
#define T_ 2048
#define E_ 1024
#define H_ 16
#define D_ 64
#define BT_ (B_ * T_)   // 8192
#define NT_ 16          // K tiles for the 256^2 GEMM (K=1024, BK=64)

__device__ __forceinline__ f32x4 mfma16(bf16x8 a, bf16x8 b, f32x4 c) {
  return __builtin_amdgcn_mfma_f32_16x16x32_bf16(a, b, c, 0, 0, 0);
}

// async global->LDS, 16B per lane. LDS dest linear: base + lane*16.
__device__ __forceinline__ void gl_lds16(void* lds, const void* g) {
  __builtin_amdgcn_global_load_lds(
      (__attribute__((address_space(1))) unsigned int*)g,
      (__attribute__((address_space(3))) unsigned int*)lds, 16, 0, 0);
}

__device__ __forceinline__ uint pkbf(float a, float b) {
  ushort ux = __builtin_bit_cast(ushort, (__bf16)a);
  ushort uy = __builtin_bit_cast(ushort, (__bf16)b);
  return (uint)ux | ((uint)uy << 16);
}

// 1/sqrt(D) * log2(e), folded into the Q projection epilogue.
#define QSCL 0.18033688011112f

// ---------------------------------------------------------------- convert
__global__ __launch_bounds__(256) void cvt_bf16(const float* __restrict__ in,
                                                __bf16* __restrict__ out, int n) {
  int i = (blockIdx.x * 256 + threadIdx.x) * 8;
  if (i >= n) return;
  float4 a = *(const float4*)&in[i];
  float4 b = *(const float4*)&in[i + 4];
  bf16x8 o;
  o[0] = (__bf16)a.x; o[1] = (__bf16)a.y; o[2] = (__bf16)a.z; o[3] = (__bf16)a.w;
  o[4] = (__bf16)b.x; o[5] = (__bf16)b.y; o[6] = (__bf16)b.z; o[7] = (__bf16)b.w;
  *(bf16x8*)&out[i] = o;
}

// all four 1024x1024 weight matrices in one launch (y picks the matrix)
__global__ __launch_bounds__(256) void cvt_w4(const float* __restrict__ w0,
                                              const float* __restrict__ w1,
                                              const float* __restrict__ w2,
                                              const float* __restrict__ w3,
                                              __bf16* __restrict__ o0,
                                              __bf16* __restrict__ o1,
                                              __bf16* __restrict__ o2,
                                              __bf16* __restrict__ o3) {
  const float* in;
  __bf16* out;
  switch (blockIdx.y) {
    case 0: in = w0; out = o0; break;
    case 1: in = w1; out = o1; break;
    case 2: in = w2; out = o2; break;
    default: in = w3; out = o3; break;
  }
  int i = (blockIdx.x * 256 + threadIdx.x) * 8;
  float4 a = *(const float4*)&in[i];
  float4 b = *(const float4*)&in[i + 4];
  bf16x8 o;
  o[0] = (__bf16)a.x; o[1] = (__bf16)a.y; o[2] = (__bf16)a.z; o[3] = (__bf16)a.w;
  o[4] = (__bf16)b.x; o[5] = (__bf16)b.y; o[6] = (__bf16)b.z; o[7] = (__bf16)b.w;
  *(bf16x8*)&out[i] = o;
}

// ------------------------------------------------ 256^2 8-phase GEMM core
// C[m][n] = sum_k A[m][k]*B[n][k].  BM=BN=256, BK=64, 8 waves (2M x 4N),
// 512 threads, LDS 128KB dynamic: [dbuf p][A/B][half h][128 rows x 64 cols].
// Per K-tile: 4 phases; phase q computes m-frags {2q,2q+1} x 4 n-frags x
// 2 kk = 16 MFMA/wave.  B-frags read once at q==0 (held in regs).
//
// Half-tile ring (item s = 4*tau + j; j 0,1 = B half j, j 2,3 = A half j-2;
// slot p = tau&1): stage item s at global phase P = s - 6.
//   B slot of tau freed after phase 4(tau-2)+0 (B read only at q==0);
//     staged at 4tau-6 = 4(tau-2)+2  -> safe.
//   A slot of tau freed after phase 4(tau-2)+3; staged at 4tau-4 -> safe.
// Tile-boundary wait (end of q==3): tile tau+1's items are staged by phase
// 4tau+1; the 4 newest loads (phases 4tau+2,3 = items of tiles tau+2) may
// stay in flight -> s_waitcnt vmcnt(4), never 0 (T4). Last 2 tiles: staging
// has ceased so the newest-4 window regresses into needed items -> vmcnt(0).
// Swizzle: 128B rows, phys chunk = logical ^ (row&7) both sides (rule #21;
// attn-verified) -> ds_read_b128 2-way max (free, m136).
__device__ __forceinline__ void g256_core(const __bf16* __restrict__ Ag,
                                          const __bf16* __restrict__ Bg,
                                          int m0, int n0, __bf16* smem,
                                          int tid, f32x4 (&acc)[8][4]) {
  const int lane = tid & 63;
  const int wv = tid >> 6;
  const int fr = lane & 15;
  const int g = lane >> 4;
  const int hA = wv >> 2;          // A half (wr = hA*128)
  const int wcq = wv & 3;          // B quadrant; wc = wcq*64
  const int hB = wcq >> 1;
  const int lb0 = (wcq & 1) << 6;  // B row base within its half
  const int K = E_;

  auto slot = [&](int p, int ab, int h) -> __bf16* {
    return smem + (((p * 2 + ab) * 2 + h) * (128 * 64));
  };

  auto stage_item = [&](int s) {
    const int tau = s >> 2, j = s & 3, p = tau & 1;
    const int k0 = tau << 6;
#pragma unroll
    for (int rr = 0; rr < 2; ++rr) {
      const int idx = rr * 512 + tid;  // 0..1023 -> 16KB half-tile
      const int row = idx >> 3, pc = idx & 7;
      const int gc = (pc ^ (row & 7)) << 3;  // pre-swizzled global chunk
      if (j < 2)
        gl_lds16(slot(p, 1, j) + idx * 8,
                 Bg + (size_t)(n0 + j * 128 + row) * K + k0 + gc);
      else
        gl_lds16(slot(p, 0, j - 2) + idx * 8,
                 Ag + (size_t)(m0 + (j - 2) * 128 + row) * K + k0 + gc);
    }
  };

  // prologue: items 0..5 (tile 0 complete + B of tile 1); first 4 landed.
  for (int s = 0; s < 6; ++s) stage_item(s);
  asm volatile("s_waitcnt vmcnt(4)" ::: "memory");
  asm volatile("s_barrier" ::: "memory");

#pragma unroll 1
  for (int tau = 0; tau < NT_; ++tau) {
    const int p = tau & 1;
    const __bf16* sa = slot(p, 0, hA);
    const __bf16* sb = slot(p, 1, hB);
    bf16x8 bq[4][2];
#pragma unroll
    for (int q = 0; q < 4; ++q) {
      if (q == 0) {
#pragma unroll
        for (int ni = 0; ni < 4; ++ni)
#pragma unroll
          for (int kk = 0; kk < 2; ++kk) {
            const int lr = lb0 + ni * 16 + fr;
            bq[ni][kk] =
                *(const bf16x8*)&sb[lr * 64 + (((kk * 4 + g) ^ (lr & 7)) << 3)];
          }
      }
      bf16x8 af[2][2];
#pragma unroll
      for (int a = 0; a < 2; ++a)
#pragma unroll
        for (int kk = 0; kk < 2; ++kk) {
          const int lr = (2 * q + a) * 16 + fr;
          af[a][kk] =
              *(const bf16x8*)&sa[lr * 64 + (((kk * 4 + g) ^ (lr & 7)) << 3)];
        }
      const int s = tau * 4 + q + 6;
      if (s < 4 * NT_) stage_item(s);
      asm volatile("s_barrier" ::: "memory");
      __builtin_amdgcn_s_setprio(1);
#pragma unroll
      for (int a = 0; a < 2; ++a)
#pragma unroll
        for (int kk = 0; kk < 2; ++kk)
#pragma unroll
          for (int ni = 0; ni < 4; ++ni)
            acc[2 * q + a][ni] =
                mfma16(af[a][kk], bq[ni][kk], acc[2 * q + a][ni]);
      __builtin_amdgcn_s_setprio(0);
      if (q == 3) {
        if (tau >= NT_ - 2)
          asm volatile("s_waitcnt vmcnt(0)" ::: "memory");
        else
          asm volatile("s_waitcnt vmcnt(4)" ::: "memory");
      }
      asm volatile("s_barrier" ::: "memory");
    }
  }
}

// Fused QKV projections, 256^2 8-phase. Grid (32, 4, 3); x = token-tile so
// blocks sharing an x-panel (ids differ by 32/64) land on the same XCD.
// z=0: Q = (x Wq^T + bq) * QSCL -> bf16 scatter [B,H,T,D]
// z=1: K = x Wk^T + bk          -> bf16 scatter [B,H,T,D]
// z=2: V^T = Wv x^T + bv        -> bf16 scatter [B,H,D,T]  (operands swapped)
__global__ __launch_bounds__(512, 1) void gemm256_qkv(
    const __bf16* __restrict__ xb, const __bf16* __restrict__ Wq,
    const __bf16* __restrict__ Wk, const __bf16* __restrict__ Wv,
    const float* __restrict__ bq, const float* __restrict__ bk,
    const float* __restrict__ bv, __bf16* __restrict__ Qb,
    __bf16* __restrict__ Kb, __bf16* __restrict__ Vtb) {
  extern __shared__ __bf16 smem[];
  const int z = blockIdx.z;
  const __bf16* A;
  const __bf16* Bm;
  const float* bias;
  int m0, n0;
  if (z == 0) {
    A = xb; Bm = Wq; bias = bq;
    m0 = blockIdx.x * 256; n0 = blockIdx.y * 256;
  } else if (z == 1) {
    A = xb; Bm = Wk; bias = bk;
    m0 = blockIdx.x * 256; n0 = blockIdx.y * 256;
  } else {
    A = Wv; Bm = xb; bias = bv;  // V^T: m = embed, n = token
    m0 = blockIdx.y * 256; n0 = blockIdx.x * 256;
  }

  f32x4 acc[8][4] = {};
  g256_core(A, Bm, m0, n0, smem, threadIdx.x, acc);

  const int lane = threadIdx.x & 63;
  const int wv = threadIdx.x >> 6;
  const int fr = lane & 15, g = lane >> 4;
  const int wr = (wv >> 2) * 128, wc = (wv & 3) * 64;
#pragma unroll
  for (int mi = 0; mi < 8; ++mi)
#pragma unroll
    for (int ni = 0; ni < 4; ++ni)
#pragma unroll
      for (int r = 0; r < 4; ++r) {
        const int m = m0 + wr + mi * 16 + g * 4 + r;
        const int n = n0 + wc + ni * 16 + fr;
        float v = acc[mi][ni][r];
        if (z == 2) {
          v += bias[m];
          const int b = n >> 11, t = n & (T_ - 1);
          const int hh = m >> 6, d = m & 63;
          Vtb[(((size_t)b * H_ + hh) * D_ + d) * T_ + t] = (__bf16)v;
        } else {
          v += bias[n];
          if (z == 0) v *= QSCL;
          const int b = m >> 11, t = m & (T_ - 1);
          const int hh = n >> 6, d = n & 63;
          __bf16* o = (z == 0) ? Qb : Kb;
          o[(((size_t)b * H_ + hh) * T_ + t) * D_ + d] = (__bf16)v;
        }
      }
}

// Output projection, 256^2 8-phase: C = O Wo^T + bo, fp32 out. Grid (32, 4).
__global__ __launch_bounds__(512, 1) void gemm256_out(
    const __bf16* __restrict__ Ao, const __bf16* __restrict__ Wo,
    const float* __restrict__ bias, float* __restrict__ out) {
  extern __shared__ __bf16 smem[];
  const int m0 = blockIdx.x * 256, n0 = blockIdx.y * 256;

  f32x4 acc[8][4] = {};
  g256_core(Ao, Wo, m0, n0, smem, threadIdx.x, acc);

  const int lane = threadIdx.x & 63;
  const int wv = threadIdx.x >> 6;
  const int fr = lane & 15, g = lane >> 4;
  const int wr = (wv >> 2) * 128, wc = (wv & 3) * 64;
#pragma unroll
  for (int mi = 0; mi < 8; ++mi)
#pragma unroll
    for (int ni = 0; ni < 4; ++ni)
#pragma unroll
      for (int r = 0; r < 4; ++r) {
        const int m = m0 + wr + mi * 16 + g * 4 + r;
        const int n = n0 + wc + ni * 16 + fr;
        out[(size_t)m * E_ + n] = acc[mi][ni][r] + bias[n];
      }
}

// ---------------------------------------------------------------- attention
// r12 attn verbatim (90.4 µs measured). Q,K: [B,H,T,D] bf16 (Q pre-scaled
// by QSCL). Vt: [B,H,D,T]. 8 waves x 16 q-rows, 512 paired blocks
// (supertile pair pr,15-pr), KVBLK=128, K/V staged once per block
// (XOR-chunk swizzle, rule #21), head->XCD pinning, swapped QK^T,
// partial-vote defer-max, bpermute P-redistribution.
__global__ __launch_bounds__(512) void attn_fwd(const __bf16* __restrict__ Q,
                                                const __bf16* __restrict__ Kg,
                                                const __bf16* __restrict__ Vt,
                                                __bf16* __restrict__ O) {
  __shared__ __bf16 sK[2][128 * 64];  // [kv][d], chunk-swizzled (16KB each)
  __shared__ __bf16 sV[2][64 * 128];  // [d][kv], chunk-swizzled (16KB each)
  const int tid = threadIdx.x;
  const int lane = tid & 63;
  const int wv = tid >> 6;  // wave 0..7 -> q rows 16*wv..+16 of the supertile
  const int fr = lane & 15;
  const int g = lane >> 4;
  const int k = blockIdx.x;
  const int bh = (k & 7) | ((k >> 6) << 3);  // head pinned to xcd = bh%8
  const int pr = (k >> 3) & 7;               // supertile pair index
  const __bf16* Qp = Q + (size_t)bh * T_ * D_;
  const __bf16* Kp = Kg + (size_t)bh * T_ * D_;
  const __bf16* Vp = Vt + (size_t)bh * D_ * T_;
  const int addrA = (fr + 32 * (g & 1)) * 4;  // bpermute base (bytes)
  const int b = bh >> 4, h = bh & 15;

  auto stage = [&](int buf, int kv0) {
#pragma unroll
    for (int rr = 0; rr < 2; ++rr) {
      const int idx = rr * 512 + tid;  // 0..1023
      const int krow = idx >> 3, kch = idx & 7;
      gl_lds16(&sK[buf][idx * 8],
               Kp + (size_t)(kv0 + krow) * D_ + ((kch ^ (krow & 7)) << 3));
      const int vrow = idx >> 4, vch = idx & 15;
      gl_lds16(&sV[buf][idx * 8],
               Vp + (size_t)vrow * T_ + kv0 + ((vch ^ (vrow & 15)) << 3));
    }
  };

#pragma unroll 1
  for (int pass = 0; pass < 2; ++pass) {
    const int s = pass ? 15 - pr : pr;   // supertile (128 q rows)
    const int qw = s * 128 + wv * 16;    // this wave's 16-row q base
    const int ntile = s + 1;             // 128-kv tiles

    // Q B-frags: lane holds Q[qw+fr][kc*32 + g*8 + j]
    bf16x8 qf[2];
#pragma unroll
    for (int kc = 0; kc < 2; kc++)
      qf[kc] = *(const bf16x8*)&Qp[(size_t)(qw + fr) * D_ + kc * 32 + g * 8];

    f32x4 acc[4] = {};       // O[q=qw+g*4+r][d=nd*16+fr]
    float mrun = -INFINITY;  // per-lane q-row (fr) stats
    float lrun = 0.f;

    stage(0, 0);
    __syncthreads();
    int cur = 0;

#pragma unroll 1
    for (int kt = 0; kt < ntile; ++kt) {
      const int kv0 = kt << 7;
      if (kt + 1 < ntile) stage(cur ^ 1, (kt + 1) << 7);  // prefetch next

      // ---- S^T = K . Q^T  (K frags from swizzled LDS)
      f32x4 st[8] = {};  // [kvf]: S^T[kv=kv0+kvf*16+g*4+r][q=qw+fr]
      __builtin_amdgcn_s_setprio(1);
#pragma unroll
      for (int kvf = 0; kvf < 8; ++kvf) {
        const int row = kvf * 16 + fr;
        bf16x8 kf0 = *(const bf16x8*)&sK[cur][row * 64 + ((g ^ (fr & 7)) << 3)];
        bf16x8 kf1 =
            *(const bf16x8*)&sK[cur][row * 64 + (((g + 4) ^ (fr & 7)) << 3)];
        st[kvf] = mfma16(kf0, qf[0], st[kvf]);
        st[kvf] = mfma16(kf1, qf[1], st[kvf]);
      }
      __builtin_amdgcn_s_setprio(0);

      // ---- causal mask (only the last tile straddles this wave's rows)
      if (kv0 + 127 > qw) {
#pragma unroll
        for (int kvf = 0; kvf < 8; ++kvf)
#pragma unroll
          for (int r = 0; r < 4; ++r)
            if (kv0 + kvf * 16 + g * 4 + r > qw + fr) st[kvf][r] = -INFINITY;
      }

      // ---- online softmax (per-lane row; Q pre-scaled so st is in log2)
      float rm[8];
#pragma unroll
      for (int kvf = 0; kvf < 8; ++kvf)
        rm[kvf] =
            fmaxf(fmaxf(st[kvf][0], st[kvf][1]), fmaxf(st[kvf][2], st[kvf][3]));
      float rmax = fmaxf(fmaxf(fmaxf(rm[0], rm[1]), fmaxf(rm[2], rm[3])),
                         fmaxf(fmaxf(rm[4], rm[5]), fmaxf(rm[6], rm[7])));

      // defer-max fast path: partial-max vote, no cross-lane ops
      if (!__all(rmax - mrun <= 8.f)) {
        float rfull = fmaxf(rmax, __shfl_xor(rmax, 16, 64));
        rfull = fmaxf(rfull, __shfl_xor(rfull, 32, 64));
        const float mn = fmaxf(mrun, rfull);
        const float corr = exp2f(mrun - mn);  // 0 on first tile
        mrun = mn;
        lrun *= corr;
        float cg[4];
#pragma unroll
        for (int r = 0; r < 4; ++r) cg[r] = __shfl(corr, g * 4 + r, 64);
#pragma unroll
        for (int nd = 0; nd < 4; ++nd)
#pragma unroll
          for (int r = 0; r < 4; ++r) acc[nd][r] *= cg[r];
      }

      float p[8][4];
      float ls = 0.f;
#pragma unroll
      for (int kvf = 0; kvf < 8; ++kvf)
#pragma unroll
        for (int r = 0; r < 4; ++r) {
          p[kvf][r] = exp2f(st[kvf][r] - mrun);
          ls += p[kvf][r];
        }
      lrun += ls;

      uint w[8][2];
#pragma unroll
      for (int kvf = 0; kvf < 8; ++kvf) {
        w[kvf][0] = pkbf(p[kvf][0], p[kvf][1]);
        w[kvf][1] = pkbf(p[kvf][2], p[kvf][3]);
      }
      // redistribute to A-frag: lane needs kv = 32kc + 8g + 2m (,+1)
      uint W[4][4];
#pragma unroll
      for (int kc = 0; kc < 4; ++kc)
#pragma unroll
        for (int m = 0; m < 4; ++m) {
          const int a = addrA + (m >> 1) * 64;
          int t0 = __builtin_amdgcn_ds_bpermute(a, (int)w[2 * kc][m & 1]);
          int t1 = __builtin_amdgcn_ds_bpermute(a, (int)w[2 * kc + 1][m & 1]);
          W[kc][m] = (uint)((g >> 1) ? t1 : t0);
        }

      // ---- O += P V  (V frags from swizzled LDS)
      __builtin_amdgcn_s_setprio(1);
#pragma unroll
      for (int kc = 0; kc < 4; ++kc) {
        u32x4 t;
        t[0] = W[kc][0]; t[1] = W[kc][1]; t[2] = W[kc][2]; t[3] = W[kc][3];
        bf16x8 pa = __builtin_bit_cast(bf16x8, t);
#pragma unroll
        for (int nd = 0; nd < 4; ++nd) {
          const int row = nd * 16 + fr;
          bf16x8 vf =
              *(const bf16x8*)&sV[cur][row * 128 + (((4 * kc + g) ^ fr) << 3)];
          acc[nd] = mfma16(pa, vf, acc[nd]);
        }
      }
      __builtin_amdgcn_s_setprio(0);

      __syncthreads();  // drains stage vmcnt + protects buffer swap
      cur ^= 1;
    }

    // ---- epilogue: full row sums, divide, store [B,T,H,D]
    lrun += __shfl_xor(lrun, 16, 64);
    lrun += __shfl_xor(lrun, 32, 64);
    float linv[4];
#pragma unroll
    for (int r = 0; r < 4; ++r) linv[r] = 1.f / __shfl(lrun, g * 4 + r, 64);
#pragma unroll
    for (int nd = 0; nd < 4; ++nd)
#pragma unroll
      for (int r = 0; r < 4; ++r) {
        const int t = qw + g * 4 + r;
        O[(((size_t)b * T_ + t) * H_ + h) * D_ + nd * 16 + fr] =
            (__bf16)(acc[nd][r] * linv[r]);
      }
  }
}

// ---------------------------------------------------------------- launcher
extern "C" void kernel_launch(void* const* d_in, const int* in_sizes, int n_in,
                              void* d_out, int out_size, void* d_ws, size_t ws_size,
                              hipStream_t stream) {
  const float* x  = (const float*)d_in[0];
  const float* Wq = (const float*)d_in[1];
  const float* bq = (const float*)d_in[2];
  const float* Wk = (const float*)d_in[3];
  const float* bk = (const float*)d_in[4];
  const float* Wv = (const float*)d_in[5];
  const float* bv = (const float*)d_in[6];
  const float* Wo = (const float*)d_in[7];
  const float* bo = (const float*)d_in[8];

  char* w = (char*)d_ws;
  __bf16* xb  = (__bf16*)w; w += (size_t)BT_ * E_ * 2;
  __bf16* Wqb = (__bf16*)w; w += (size_t)E_ * E_ * 2;
  __bf16* Wkb = (__bf16*)w; w += (size_t)E_ * E_ * 2;
  __bf16* Wvb = (__bf16*)w; w += (size_t)E_ * E_ * 2;
  __bf16* Wob = (__bf16*)w; w += (size_t)E_ * E_ * 2;
  __bf16* Qb  = (__bf16*)w; w += (size_t)BT_ * E_ * 2;
  __bf16* Kb  = (__bf16*)w; w += (size_t)BT_ * E_ * 2;
  __bf16* Vtb = (__bf16*)w; w += (size_t)BT_ * E_ * 2;
  __bf16* Ob  = (__bf16*)w; w += (size_t)BT_ * E_ * 2;

  // 128KB dynamic LDS opt-in for the 256^2 GEMMs (host-side attribute set,
  // not a stream op -> graph-capture safe; idempotent).
  hipFuncSetAttribute((const void*)gemm256_qkv,
                      hipFuncAttributeMaxDynamicSharedMemorySize, 131072);
  hipFuncSetAttribute((const void*)gemm256_out,
                      hipFuncAttributeMaxDynamicSharedMemorySize, 131072);

  cvt_bf16<<<(BT_ * E_) / 2048, 256, 0, stream>>>(x, xb, BT_ * E_);
  cvt_w4<<<dim3((E_ * E_) / 2048, 4), 256, 0, stream>>>(Wq, Wk, Wv, Wo,
                                                        Wqb, Wkb, Wvb, Wob);

  gemm256_qkv<<<dim3(BT_ / 256, E_ / 256, 3), 512, 131072, stream>>>(
      xb, Wqb, Wkb, Wvb, bq, bk, bv, Qb, Kb, Vtb);

  attn_fwd<<<512, 512, 0, stream>>>(Qb, Kb, Vtb, Ob);

  gemm256_out<<<dim3(BT_ / 256, E_ / 256), 512, 131072, stream>>>(
      Ob, Wob, bo, (float*)d_out);
}

// Round 16
// 200.944 us; speedup vs baseline: 1.1206x; 1.1206x over previous
//
#include <hip/hip_runtime.h>
#include <math.h>

// Causal self-attention, B=4, T=2048, E=1024, H=16, D=64. fp32 in/out,
// bf16 MFMA internally. r16 = r12 configuration (best measured: 202 µs)
// with the two conversion kernels merged into one launch.

typedef __bf16 bf16x8 __attribute__((ext_vector_type(8)));
typedef float f32x4 __attribute__((ext_vector_type(4)));
typedef unsigned int u32x4 __attribute__((ext_vector_type(4)));
typedef unsigned int uint;
typedef unsigned short ushort;

#define B_ 4
#define T_ 2048
#define E_ 1024
#define H_ 16
#define D_ 64
#define BT_ (B_ * T_)   // 8192

__device__ __forceinline__ f32x4 mfma16(bf16x8 a, bf16x8 b, f32x4 c) {
  return __builtin_amdgcn_mfma_f32_16x16x32_bf16(a, b, c, 0, 0, 0);
}

// async global->LDS, 16B per lane. LDS dest linear: base + lane*16.
__device__ __forceinline__ void gl_lds16(void* lds, const void* g) {
  __builtin_amdgcn_global_load_lds(
      (__attribute__((address_space(1))) unsigned int*)g,
      (__attribute__((address_space(3))) unsigned int*)lds, 16, 0, 0);
}

__device__ __forceinline__ uint pkbf(float a, float b) {
  ushort ux = __builtin_bit_cast(ushort, (__bf16)a);
  ushort uy = __builtin_bit_cast(ushort, (__bf16)b);
  return (uint)ux | ((uint)uy << 16);
}

// 1/sqrt(D) * log2(e), folded into the Q projection epilogue.
#define QSCL 0.18033688011112f

// ---------------------------------------------------------------- convert
// One launch for x (4096 blocks) + the four weight matrices (4 x 512).
__global__ __launch_bounds__(256) void cvt_all(const float* __restrict__ x,
                                               const float* __restrict__ w0,
                                               const float* __restrict__ w1,
                                               const float* __restrict__ w2,
                                               const float* __restrict__ w3,
                                               __bf16* __restrict__ xo,
                                               __bf16* __restrict__ o0,
                                               __bf16* __restrict__ o1,
                                               __bf16* __restrict__ o2,
                                               __bf16* __restrict__ o3) {
  const float* in;
  __bf16* out;
  int i;
  if (blockIdx.x < 4096) {
    in = x; out = xo;
    i = (blockIdx.x * 256 + threadIdx.x) * 8;
  } else {
    const int wb = blockIdx.x - 4096;
    switch (wb >> 9) {
      case 0: in = w0; out = o0; break;
      case 1: in = w1; out = o1; break;
      case 2: in = w2; out = o2; break;
      default: in = w3; out = o3; break;
    }
    i = ((wb & 511) * 256 + threadIdx.x) * 8;
  }
  float4 a = *(const float4*)&in[i];
  float4 b = *(const float4*)&in[i + 4];
  bf16x8 o;
  o[0] = (__bf16)a.x; o[1] = (__bf16)a.y; o[2] = (__bf16)a.z; o[3] = (__bf16)a.w;
  o[4] = (__bf16)b.x; o[5] = (__bf16)b.y; o[6] = (__bf16)b.z; o[7] = (__bf16)b.w;
  *(bf16x8*)&out[i] = o;
}

// ---------------------------------------------------------------- GEMM (NT)
// r12 structure: 128^2 tile, 4 waves, BK=32, single-buffer 2-barrier loop
// (implicit cross-block overlap at ~4 blocks/CU covers the drain; r13 dbuf
// null, r14 32x32 and r15 8-phase both regressed at this shape/grid).
// Output projection: C[m][n] = sum_k A[m][k]*B[n][k] + bias[n], fp32 out.
// Grid (64, 8): x = m-tile so n-blocks sharing an A-panel land on one XCD.
__global__ __launch_bounds__(256) void gemm_out(const __bf16* __restrict__ A,
                                                const __bf16* __restrict__ Bm,
                                                const float* __restrict__ bias,
                                                float* __restrict__ out,
                                                int M, int N, int K) {
  __shared__ __bf16 sA[128 * 32];
  __shared__ __bf16 sB[128 * 32];
  const int tid = threadIdx.x;
  const int lane = tid & 63;
  const int wv = tid >> 6;
  const int wr = (wv >> 1) << 6;
  const int wc = (wv & 1) << 6;
  const int fr = lane & 15;
  const int fo = (lane >> 4) << 3;
  const int g = lane >> 4;
  const int m0 = blockIdx.x * 128;
  const int n0 = blockIdx.y * 128;

  f32x4 acc[4][4] = {};

  const __bf16* aRow = A + (size_t)(m0 + (tid >> 2)) * K + ((tid & 3) << 3);
  const __bf16* bRow = Bm + (size_t)(n0 + (tid >> 2)) * K + ((tid & 3) << 3);

  for (int kt = 0; kt < K; kt += 32) {
    gl_lds16(&sA[(size_t)tid * 8], aRow + kt);
    gl_lds16(&sA[(size_t)(256 + tid) * 8], aRow + (size_t)64 * K + kt);
    gl_lds16(&sB[(size_t)tid * 8], bRow + kt);
    gl_lds16(&sB[(size_t)(256 + tid) * 8], bRow + (size_t)64 * K + kt);
    __syncthreads();
    bf16x8 af[4], bq[4];
#pragma unroll
    for (int i = 0; i < 4; i++) af[i] = *(const bf16x8*)&sA[(wr + i * 16 + fr) * 32 + fo];
#pragma unroll
    for (int i = 0; i < 4; i++) bq[i] = *(const bf16x8*)&sB[(wc + i * 16 + fr) * 32 + fo];
#pragma unroll
    for (int i = 0; i < 4; i++)
#pragma unroll
      for (int j = 0; j < 4; j++) acc[i][j] = mfma16(af[i], bq[j], acc[i][j]);
    __syncthreads();
  }

#pragma unroll
  for (int i = 0; i < 4; i++) {
#pragma unroll
    for (int j = 0; j < 4; j++) {
#pragma unroll
      for (int r = 0; r < 4; r++) {
        const int m = m0 + wr + i * 16 + g * 4 + r;
        const int n = n0 + wc + j * 16 + fr;
        out[(size_t)m * N + n] = acc[i][j][r] + bias[n];
      }
    }
  }
}

// Fused QKV projections: grid (64, 8, 3); x = token-tile so blocks sharing
// an x-panel land on the same XCD.
// z=0: Q = (x Wq^T + bq) * QSCL -> bf16 scatter [B,H,T,D]  (scale folded)
// z=1: K = x Wk^T + bk          -> bf16 scatter [B,H,T,D]
// z=2: V^T = Wv x^T + bv        -> bf16 scatter [B,H,D,T]  (operands swapped)
__global__ __launch_bounds__(256) void gemm_qkv(const __bf16* __restrict__ xb,
                                                const __bf16* __restrict__ Wq,
                                                const __bf16* __restrict__ Wk,
                                                const __bf16* __restrict__ Wv,
                                                const float* __restrict__ bq,
                                                const float* __restrict__ bk,
                                                const float* __restrict__ bv,
                                                __bf16* __restrict__ Qb,
                                                __bf16* __restrict__ Kb,
                                                __bf16* __restrict__ Vtb) {
  __shared__ __bf16 sA[128 * 32];
  __shared__ __bf16 sB[128 * 32];
  const int z = blockIdx.z;
  const __bf16* A;
  const __bf16* Bm;
  const float* bias;
  int m0, n0;
  if (z == 0) {
    A = xb; Bm = Wq; bias = bq;
    m0 = blockIdx.x * 128; n0 = blockIdx.y * 128;
  } else if (z == 1) {
    A = xb; Bm = Wk; bias = bk;
    m0 = blockIdx.x * 128; n0 = blockIdx.y * 128;
  } else {
    A = Wv; Bm = xb; bias = bv;           // V^T: m = embed, n = token
    m0 = blockIdx.y * 128; n0 = blockIdx.x * 128;
  }
  const int K = E_;
  const int tid = threadIdx.x;
  const int lane = tid & 63;
  const int wv = tid >> 6;
  const int wr = (wv >> 1) << 6;
  const int wc = (wv & 1) << 6;
  const int fr = lane & 15;
  const int fo = (lane >> 4) << 3;
  const int g = lane >> 4;

  f32x4 acc[4][4] = {};

  const __bf16* aRow = A + (size_t)(m0 + (tid >> 2)) * K + ((tid & 3) << 3);
  const __bf16* bRow = Bm + (size_t)(n0 + (tid >> 2)) * K + ((tid & 3) << 3);

  for (int kt = 0; kt < K; kt += 32) {
    gl_lds16(&sA[(size_t)tid * 8], aRow + kt);
    gl_lds16(&sA[(size_t)(256 + tid) * 8], aRow + (size_t)64 * K + kt);
    gl_lds16(&sB[(size_t)tid * 8], bRow + kt);
    gl_lds16(&sB[(size_t)(256 + tid) * 8], bRow + (size_t)64 * K + kt);
    __syncthreads();
    bf16x8 af[4], bq4[4];
#pragma unroll
    for (int i = 0; i < 4; i++) af[i] = *(const bf16x8*)&sA[(wr + i * 16 + fr) * 32 + fo];
#pragma unroll
    for (int i = 0; i < 4; i++) bq4[i] = *(const bf16x8*)&sB[(wc + i * 16 + fr) * 32 + fo];
#pragma unroll
    for (int i = 0; i < 4; i++)
#pragma unroll
      for (int j = 0; j < 4; j++) acc[i][j] = mfma16(af[i], bq4[j], acc[i][j]);
    __syncthreads();
  }

#pragma unroll
  for (int i = 0; i < 4; i++) {
#pragma unroll
    for (int j = 0; j < 4; j++) {
#pragma unroll
      for (int r = 0; r < 4; r++) {
        const int m = m0 + wr + i * 16 + g * 4 + r;
        const int n = n0 + wc + j * 16 + fr;
        float v = acc[i][j][r];
        if (z == 2) {
          v += bias[m];
          const int b = n >> 11, t = n & (T_ - 1);
          const int h = m >> 6, d = m & 63;
          Vtb[(((size_t)b * H_ + h) * D_ + d) * T_ + t] = (__bf16)v;
        } else {
          v += bias[n];
          if (z == 0) v *= QSCL;  // fold softmax scale into Q
          const int b = m >> 11, t = m & (T_ - 1);
          const int h = n >> 6, d = n & 63;
          __bf16* out = (z == 0) ? Qb : Kb;
          out[(((size_t)b * H_ + h) * T_ + t) * D_ + d] = (__bf16)v;
        }
      }
    }
  }
}

// ---------------------------------------------------------------- attention
// r12 attn verbatim (90.4 µs measured). Q,K: [B,H,T,D] bf16 (Q pre-scaled
// by QSCL). Vt: [B,H,D,T]. 8 waves x 16 q-rows, 512 paired blocks
// (supertile pair pr,15-pr), KVBLK=128, K/V staged once per block
// (XOR-chunk swizzle, rule #21), head->XCD pinning, swapped QK^T,
// partial-vote defer-max, bpermute P-redistribution.
__global__ __launch_bounds__(512) void attn_fwd(const __bf16* __restrict__ Q,
                                                const __bf16* __restrict__ Kg,
                                                const __bf16* __restrict__ Vt,
                                                __bf16* __restrict__ O) {
  __shared__ __bf16 sK[2][128 * 64];  // [kv][d], chunk-swizzled (16KB each)
  __shared__ __bf16 sV[2][64 * 128];  // [d][kv], chunk-swizzled (16KB each)
  const int tid = threadIdx.x;
  const int lane = tid & 63;
  const int wv = tid >> 6;  // wave 0..7 -> q rows 16*wv..+16 of the supertile
  const int fr = lane & 15;
  const int g = lane >> 4;
  const int k = blockIdx.x;
  const int bh = (k & 7) | ((k >> 6) << 3);  // head pinned to xcd = bh%8
  const int pr = (k >> 3) & 7;               // supertile pair index
  const __bf16* Qp = Q + (size_t)bh * T_ * D_;
  const __bf16* Kp = Kg + (size_t)bh * T_ * D_;
  const __bf16* Vp = Vt + (size_t)bh * D_ * T_;
  const int addrA = (fr + 32 * (g & 1)) * 4;  // bpermute base (bytes)
  const int b = bh >> 4, h = bh & 15;

  auto stage = [&](int buf, int kv0) {
#pragma unroll
    for (int rr = 0; rr < 2; ++rr) {
      const int idx = rr * 512 + tid;  // 0..1023
      const int krow = idx >> 3, kch = idx & 7;
      gl_lds16(&sK[buf][idx * 8],
               Kp + (size_t)(kv0 + krow) * D_ + ((kch ^ (krow & 7)) << 3));
      const int vrow = idx >> 4, vch = idx & 15;
      gl_lds16(&sV[buf][idx * 8],
               Vp + (size_t)vrow * T_ + kv0 + ((vch ^ (vrow & 15)) << 3));
    }
  };

#pragma unroll 1
  for (int pass = 0; pass < 2; ++pass) {
    const int s = pass ? 15 - pr : pr;   // supertile (128 q rows)
    const int qw = s * 128 + wv * 16;    // this wave's 16-row q base
    const int ntile = s + 1;             // 128-kv tiles

    // Q B-frags: lane holds Q[qw+fr][kc*32 + g*8 + j]
    bf16x8 qf[2];
#pragma unroll
    for (int kc = 0; kc < 2; kc++)
      qf[kc] = *(const bf16x8*)&Qp[(size_t)(qw + fr) * D_ + kc * 32 + g * 8];

    f32x4 acc[4] = {};       // O[q=qw+g*4+r][d=nd*16+fr]
    float mrun = -INFINITY;  // per-lane q-row (fr) stats
    float lrun = 0.f;

    stage(0, 0);
    __syncthreads();
    int cur = 0;

#pragma unroll 1
    for (int kt = 0; kt < ntile; ++kt) {
      const int kv0 = kt << 7;
      if (kt + 1 < ntile) stage(cur ^ 1, (kt + 1) << 7);  // prefetch next

      // ---- S^T = K . Q^T  (K frags from swizzled LDS)
      f32x4 st[8] = {};  // [kvf]: S^T[kv=kv0+kvf*16+g*4+r][q=qw+fr]
      __builtin_amdgcn_s_setprio(1);
#pragma unroll
      for (int kvf = 0; kvf < 8; ++kvf) {
        const int row = kvf * 16 + fr;
        bf16x8 kf0 = *(const bf16x8*)&sK[cur][row * 64 + ((g ^ (fr & 7)) << 3)];
        bf16x8 kf1 =
            *(const bf16x8*)&sK[cur][row * 64 + (((g + 4) ^ (fr & 7)) << 3)];
        st[kvf] = mfma16(kf0, qf[0], st[kvf]);
        st[kvf] = mfma16(kf1, qf[1], st[kvf]);
      }
      __builtin_amdgcn_s_setprio(0);

      // ---- causal mask (only the last tile straddles this wave's rows)
      if (kv0 + 127 > qw) {
#pragma unroll
        for (int kvf = 0; kvf < 8; ++kvf)
#pragma unroll
          for (int r = 0; r < 4; ++r)
            if (kv0 + kvf * 16 + g * 4 + r > qw + fr) st[kvf][r] = -INFINITY;
      }

      // ---- online softmax (per-lane row; Q pre-scaled so st is in log2)
      float rm[8];
#pragma unroll
      for (int kvf = 0; kvf < 8; ++kvf)
        rm[kvf] =
            fmaxf(fmaxf(st[kvf][0], st[kvf][1]), fmaxf(st[kvf][2], st[kvf][3]));
      float rmax = fmaxf(fmaxf(fmaxf(rm[0], rm[1]), fmaxf(rm[2], rm[3])),
                         fmaxf(fmaxf(rm[4], rm[5]), fmaxf(rm[6], rm[7])));

      // defer-max fast path: partial-max vote, no cross-lane ops
      if (!__all(rmax - mrun <= 8.f)) {
        float rfull = fmaxf(rmax, __shfl_xor(rmax, 16, 64));
        rfull = fmaxf(rfull, __shfl_xor(rfull, 32, 64));
        const float mn = fmaxf(mrun, rfull);
        const float corr = exp2f(mrun - mn);  // 0 on first tile
        mrun = mn;
        lrun *= corr;
        float cg[4];
#pragma unroll
        for (int r = 0; r < 4; ++r) cg[r] = __shfl(corr, g * 4 + r, 64);
#pragma unroll
        for (int nd = 0; nd < 4; ++nd)
#pragma unroll
          for (int r = 0; r < 4; ++r) acc[nd][r] *= cg[r];
      }

      float p[8][4];
      float ls = 0.f;
#pragma unroll
      for (int kvf = 0; kvf < 8; ++kvf)
#pragma unroll
        for (int r = 0; r < 4; ++r) {
          p[kvf][r] = exp2f(st[kvf][r] - mrun);
          ls += p[kvf][r];
        }
      lrun += ls;

      uint w[8][2];
#pragma unroll
      for (int kvf = 0; kvf < 8; ++kvf) {
        w[kvf][0] = pkbf(p[kvf][0], p[kvf][1]);
        w[kvf][1] = pkbf(p[kvf][2], p[kvf][3]);
      }
      // redistribute to A-frag: lane needs kv = 32kc + 8g + 2m (,+1)
      uint W[4][4];
#pragma unroll
      for (int kc = 0; kc < 4; ++kc)
#pragma unroll
        for (int m = 0; m < 4; ++m) {
          const int a = addrA + (m >> 1) * 64;
          int t0 = __builtin_amdgcn_ds_bpermute(a, (int)w[2 * kc][m & 1]);
          int t1 = __builtin_amdgcn_ds_bpermute(a, (int)w[2 * kc + 1][m & 1]);
          W[kc][m] = (uint)((g >> 1) ? t1 : t0);
        }

      // ---- O += P V  (V frags from swizzled LDS)
      __builtin_amdgcn_s_setprio(1);
#pragma unroll
      for (int kc = 0; kc < 4; ++kc) {
        u32x4 t;
        t[0] = W[kc][0]; t[1] = W[kc][1]; t[2] = W[kc][2]; t[3] = W[kc][3];
        bf16x8 pa = __builtin_bit_cast(bf16x8, t);
#pragma unroll
        for (int nd = 0; nd < 4; ++nd) {
          const int row = nd * 16 + fr;
          bf16x8 vf =
              *(const bf16x8*)&sV[cur][row * 128 + (((4 * kc + g) ^ fr) << 3)];
          acc[nd] = mfma16(pa, vf, acc[nd]);
        }
      }
      __builtin_amdgcn_s_setprio(0);

      __syncthreads();  // drains stage vmcnt + protects buffer swap
      cur ^= 1;
    }

    // ---- epilogue: full row sums, divide, store [B,T,H,D]
    lrun += __shfl_xor(lrun, 16, 64);
    lrun += __shfl_xor(lrun, 32, 64);
    float linv[4];
#pragma unroll
    for (int r = 0; r < 4; ++r) linv[r] = 1.f / __shfl(lrun, g * 4 + r, 64);
#pragma unroll
    for (int nd = 0; nd < 4; ++nd)
#pragma unroll
      for (int r = 0; r < 4; ++r) {
        const int t = qw + g * 4 + r;
        O[(((size_t)b * T_ + t) * H_ + h) * D_ + nd * 16 + fr] =
            (__bf16)(acc[nd][r] * linv[r]);
      }
  }
}

// ---------------------------------------------------------------- launcher
extern "C" void kernel_launch(void* const* d_in, const int* in_sizes, int n_in,
                              void* d_out, int out_size, void* d_ws, size_t ws_size,
                              hipStream_t stream) {
  const float* x  = (const float*)d_in[0];
  const float* Wq = (const float*)d_in[1];
  const float* bq = (const float*)d_in[2];
  const float* Wk = (const float*)d_in[3];
  const float* bk = (const float*)d_in[4];
  const float* Wv = (const float*)d_in[5];
  const float* bv = (const float*)d_in[6];
  const float* Wo = (const float*)d_in[7];
  const float* bo = (const float*)d_in[8];

  char* w = (char*)d_ws;
  __bf16* xb  = (__bf16*)w; w += (size_t)BT_ * E_ * 2;
  __bf16* Wqb = (__bf16*)w; w += (size_t)E_ * E_ * 2;
  __bf16* Wkb = (__bf16*)w; w += (size_t)E_ * E_ * 2;
  __bf16* Wvb = (__bf16*)w; w += (size_t)E_ * E_ * 2;
  __bf16* Wob = (__bf16*)w; w += (size_t)E_ * E_ * 2;
  __bf16* Qb  = (__bf16*)w; w += (size_t)BT_ * E_ * 2;
  __bf16* Kb  = (__bf16*)w; w += (size_t)BT_ * E_ * 2;
  __bf16* Vtb = (__bf16*)w; w += (size_t)BT_ * E_ * 2;
  __bf16* Ob  = (__bf16*)w; w += (size_t)BT_ * E_ * 2;

  cvt_all<<<4096 + 2048, 256, 0, stream>>>(x, Wq, Wk, Wv, Wo,
                                           xb, Wqb, Wkb, Wvb, Wob);

  gemm_qkv<<<dim3(BT_ / 128, E_ / 128, 3), 256, 0, stream>>>(
      xb, Wqb, Wkb, Wvb, bq, bk, bv, Qb, Kb, Vtb);

  attn_fwd<<<512, 512, 0, stream>>>(Qb, Kb, Vtb, Ob);

  gemm_out<<<dim3(BT_ / 128, E_ / 128), 256, 0, stream>>>(
      Ob, Wob, bo, (float*)d_out, BT_, E_, E_);
}